// Round 6
// baseline (203.734 us; speedup 1.0000x reference)
//
#include <hip/hip_runtime.h>

#define EPS 1e-6f
#define LL 4096
#define HE 512

typedef __attribute__((ext_vector_type(8))) short short8;
typedef __attribute__((ext_vector_type(4))) float f32x4;

__device__ __forceinline__ unsigned short f2bf(float f) {
    union { float f; unsigned u; } v; v.f = f;
    unsigned r = v.u + 0x7FFFu + ((v.u >> 16) & 1u);  // RNE
    return (unsigned short)(r >> 16);
}
__device__ __forceinline__ float bf2f(unsigned short s) {
    union { unsigned u; float f; } v; v.u = ((unsigned)s) << 16;
    return v.f;
}
// async global->LDS, 16B per lane; LDS dest = wave-uniform base + lane*16
__device__ __forceinline__ void gl16(const unsigned short* g, unsigned short* l) {
    __builtin_amdgcn_global_load_lds(
        (const __attribute__((address_space(1))) unsigned int*)(const void*)g,
        (__attribute__((address_space(3))) unsigned int*)(void*)l,
        16, 0, 0);
}

// ---- k1: pure streaming: q -> Vb (bf16 [l][n]) + column-stat partials ----
__global__ __launch_bounds__(256) void k1_stream(const float* __restrict__ q,
        unsigned short* __restrict__ Vb, float* __restrict__ ps,
        float* __restrict__ pq) {
    __shared__ float lds_s[4][512];
    __shared__ float lds_q[4][512];
    int blk = blockIdx.x;
    int b = blk >> 6, lt = blk & 63;
    int t = threadIdx.x;
    int oct = t & 63, w = t >> 6;
    size_t rowbase = (size_t)b * LL + lt * 64 + w * 16;
    const float* qb = q + rowbase * HE + oct * 8;
    unsigned short* vb = Vb + rowbase * HE + oct * 8;
    float s[8] = {}, qq[8] = {};
    #pragma unroll
    for (int r = 0; r < 16; r++) {
        float4 v0 = *(const float4*)(qb + (size_t)r * HE);
        float4 v1 = *(const float4*)(qb + (size_t)r * HE + 4);
        unsigned short e[8] = {f2bf(v0.x), f2bf(v0.y), f2bf(v0.z), f2bf(v0.w),
                               f2bf(v1.x), f2bf(v1.y), f2bf(v1.z), f2bf(v1.w)};
        short8 w8;
        #pragma unroll
        for (int c = 0; c < 8; c++) {
            w8[c] = (short)e[c];
            float x = bf2f(e[c]);
            s[c] += x; qq[c] += x * x;
        }
        *(short8*)(vb + (size_t)r * HE) = w8;
    }
    #pragma unroll
    for (int c = 0; c < 8; c++) {
        lds_s[w][oct * 8 + c] = s[c];
        lds_q[w][oct * 8 + c] = qq[c];
    }
    __syncthreads();
    #pragma unroll
    for (int h = 0; h < 2; h++) {
        int col = h * 256 + t;
        float ss = lds_s[0][col] + lds_s[1][col] + lds_s[2][col] + lds_s[3][col];
        float sq = lds_q[0][col] + lds_q[1][col] + lds_q[2][col] + lds_q[3][col];
        ps[(size_t)lt * 8192 + b * 512 + col] = ss;
        pq[(size_t)lt * 8192 + b * 512 + col] = sq;
    }
}

// ---- k2: reduce partials -> sumV, cvec, invn ----------------------------
__global__ __launch_bounds__(256) void k2_reduce(const float* __restrict__ ps,
        const float* __restrict__ pq, float* __restrict__ sumV,
        float* __restrict__ cvec, float* __restrict__ invn) {
    int i = blockIdx.x * 256 + threadIdx.x;   // 0..8191 = b*512 + n
    float s = 0.f, qq = 0.f;
    #pragma unroll 8
    for (int lt = 0; lt < 64; lt++) {
        s  += ps[(size_t)lt * 8192 + i];
        qq += pq[(size_t)lt * 8192 + i];
    }
    float inv = 1.0f / sqrtf(qq);
    sumV[i] = s;
    invn[i] = inv;
    cvec[i] = (s * inv + EPS) * inv;
}

// ---- k3: dvec[b,l] = sum_n Vb[l,n]*cvec[n]  (GEMV) ----------------------
__global__ __launch_bounds__(256) void k3_dvec(const unsigned short* __restrict__ Vb,
        const float* __restrict__ cvec, float* __restrict__ dvec) {
    int blk = blockIdx.x;
    int b = blk >> 7, lblk = blk & 127;
    int t = threadIdx.x;
    int lloc = t >> 3, j = t & 7;
    int l = lblk * 32 + lloc;
    const unsigned short* rowp = Vb + ((size_t)b * LL + l) * HE + j * 64;
    const float* cp = cvec + b * HE + j * 64;
    float d = 0.f;
    #pragma unroll
    for (int g = 0; g < 8; g++) {
        short8 v = *(const short8*)(rowp + g * 8);
        float4 c0 = *(const float4*)(cp + g * 8);
        float4 c1 = *(const float4*)(cp + g * 8 + 4);
        d += bf2f((unsigned short)v[0]) * c0.x + bf2f((unsigned short)v[1]) * c0.y
           + bf2f((unsigned short)v[2]) * c0.z + bf2f((unsigned short)v[3]) * c0.w
           + bf2f((unsigned short)v[4]) * c1.x + bf2f((unsigned short)v[5]) * c1.y
           + bf2f((unsigned short)v[6]) * c1.z + bf2f((unsigned short)v[7]) * c1.w;
    }
    d += __shfl_xor(d, 1); d += __shfl_xor(d, 2); d += __shfl_xor(d, 4);
    if (j == 0) dvec[(size_t)b * LL + l] = d;
}

// ---- k4: Gram partials from Vb directly (reg-staged in-LDS transpose) ---
// A,B tiles stored [n][l^swz] in LDS; T14 split: next-tile loads fly under MFMA.
__global__ __launch_bounds__(256) void k4_gram(const unsigned short* __restrict__ Vb,
        unsigned short* __restrict__ Gp) {
    __shared__ __attribute__((aligned(16))) unsigned short lt_a[128][72];
    __shared__ __attribute__((aligned(16))) unsigned short lt_b[128][72];
    int cpx = gridDim.x >> 3;
    int blk = ((int)blockIdx.x & 7) * cpx + ((int)blockIdx.x >> 3);  // XCD swizzle
    int b = blk / 80;
    int rem = blk - b * 80;
    int pair = rem >> 3, split = rem & 7;
    int nt = (pair < 4) ? 0 : (pair < 7) ? 1 : (pair < 9) ? 2 : 3;
    int off = (nt * (9 - nt)) >> 1;
    int mt = nt + pair - off;
    bool diag = (nt == mt);
    int N0 = nt * 128, M0 = mt * 128;
    int t = threadIdx.x;
    int w = t >> 6, lane = t & 63;
    int wr = w >> 1, wc = w & 1;
    int lr = lane & 15, q4 = lane >> 4;
    // staging map: 16 n-octets x 16 l-groups (4 rows each)
    int oct = t & 15;
    int l0 = (t >> 4) * 4;
    int lp = l0 ^ (8 * (oct & 7));   // XOR-swizzled l position
    const unsigned short* pa = Vb + ((size_t)b * LL + split * 512) * HE + N0 + oct * 8;
    const unsigned short* pb = Vb + ((size_t)b * LL + split * 512) * HE + M0 + oct * 8;
    f32x4 acc[4][4] = {};
    short8 ra[4], rb[4];

#define K4LOAD(KB) do { \
    _Pragma("unroll") \
    for (int r = 0; r < 4; r++) { \
        size_t ro = (size_t)((KB) * 64 + l0 + r) * HE; \
        ra[r] = *(const short8*)(pa + ro); \
        if (!diag) rb[r] = *(const short8*)(pb + ro); \
    } } while (0)

#define K4WRITE() do { \
    _Pragma("unroll") \
    for (int c = 0; c < 8; c++) { \
        uint2 da; \
        da.x = (unsigned)(unsigned short)ra[0][c] | ((unsigned)(unsigned short)ra[1][c] << 16); \
        da.y = (unsigned)(unsigned short)ra[2][c] | ((unsigned)(unsigned short)ra[3][c] << 16); \
        *(uint2*)&lt_a[oct * 8 + c][lp] = da; \
        if (!diag) { \
            uint2 db; \
            db.x = (unsigned)(unsigned short)rb[0][c] | ((unsigned)(unsigned short)rb[1][c] << 16); \
            db.y = (unsigned)(unsigned short)rb[2][c] | ((unsigned)(unsigned short)rb[3][c] << 16); \
            *(uint2*)&lt_b[oct * 8 + c][lp] = db; \
        } \
    } } while (0)

    K4LOAD(0);
    #pragma unroll
    for (int kb = 0; kb < 8; kb++) {
        if (kb) __builtin_amdgcn_s_barrier();   // prev MFMA operands already in VGPRs
        K4WRITE();
        if (kb < 7) K4LOAD(kb + 1);             // flies under this kb's MFMA
        asm volatile("s_waitcnt lgkmcnt(0)" ::: "memory");
        __builtin_amdgcn_s_barrier();
        #pragma unroll
        for (int ks = 0; ks < 2; ks++) {
            short8 af[4], bfr[4];
            #pragma unroll
            for (int i = 0; i < 4; i++) {
                int row = wr * 64 + i * 16 + lr;
                int col = (ks * 32 + q4 * 8) ^ (8 * ((2 * i + (lr >> 3)) & 7));
                af[i] = *(const short8*)&lt_a[row][col];
            }
            #pragma unroll
            for (int j = 0; j < 4; j++) {
                int row = wc * 64 + j * 16 + lr;
                int col = (ks * 32 + q4 * 8) ^ (8 * ((2 * j + (lr >> 3)) & 7));
                bfr[j] = diag ? *(const short8*)&lt_a[row][col]
                              : *(const short8*)&lt_b[row][col];
            }
            #pragma unroll
            for (int i = 0; i < 4; i++)
                #pragma unroll
                for (int j = 0; j < 4; j++)
                    acc[i][j] = __builtin_amdgcn_mfma_f32_16x16x32_bf16(af[i], bfr[j], acc[i][j], 0, 0, 0);
        }
    }
#undef K4LOAD
#undef K4WRITE
    // store bf16 partials, layout [ml*128 + nl] -> ushort4 along n
    size_t tbase = ((size_t)(b * 10 + pair) * 8 + split) * 16384;
    #pragma unroll
    for (int i = 0; i < 4; i++) {
        int nb = wr * 64 + i * 16 + q4 * 4;
        #pragma unroll
        for (int j = 0; j < 4; j++) {
            int ml = wc * 64 + j * 16 + lr;
            ushort4 wv;
            wv.x = f2bf(acc[i][j][0]); wv.y = f2bf(acc[i][j][1]);
            wv.z = f2bf(acc[i][j][2]); wv.w = f2bf(acc[i][j][3]);
            *(ushort4*)&Gp[tbase + (size_t)ml * 128 + nb] = wv;
        }
    }
}

// ---- k5: sum splits, scale by invn outer, write KQb both orientations ---
__global__ __launch_bounds__(256) void k5_reduce(const unsigned short* __restrict__ Gp,
        const float* __restrict__ invn, unsigned short* __restrict__ KQb) {
    __shared__ unsigned short lds_t[128][130];
    int blk = blockIdx.x;
    int b = blk / 10, pair = blk % 10;
    int nt = (pair < 4) ? 0 : (pair < 7) ? 1 : (pair < 9) ? 2 : 3;
    int off = (nt * (9 - nt)) >> 1;
    int mt = nt + pair - off;
    int N0 = nt * 128, M0 = mt * 128;
    int t = threadIdx.x;
    const unsigned short* gp = Gp + ((size_t)(b * 10 + pair) * 8) * 16384;
    const float* inb = invn + (size_t)b * HE;
    #pragma unroll 2
    for (int e = 0; e < 32; e++) {
        int idx = e * 512 + t * 2;           // [ml][nl] pairs
        int ml = idx >> 7, nl = idx & 127;
        float s0 = 0.f, s1 = 0.f;
        #pragma unroll
        for (int sp = 0; sp < 8; sp++) {
            unsigned g2 = *(const unsigned*)&gp[(size_t)sp * 16384 + idx];
            s0 += bf2f((unsigned short)(g2 & 0xFFFF));
            s1 += bf2f((unsigned short)(g2 >> 16));
        }
        float im = inb[M0 + ml];
        ushort2 v;
        v.x = f2bf(s0 * inb[N0 + nl] * im);
        v.y = f2bf(s1 * inb[N0 + nl + 1] * im);
        *(ushort2*)&KQb[((size_t)b * HE + M0 + ml) * HE + N0 + nl] = v;
        *(ushort2*)&lds_t[ml][nl] = v;
    }
    __syncthreads();
    #pragma unroll 2
    for (int e = 0; e < 32; e++) {
        int idx = e * 512 + t * 2;
        int nl = idx >> 7, ml = idx & 127;   // transposed roles
        ushort2 v;
        v.x = lds_t[ml][nl];
        v.y = lds_t[ml + 1][nl];
        *(ushort2*)&KQb[((size_t)b * HE + N0 + nl) * HE + M0 + ml] = v;
    }
}

// ---- k6: part GEMM (KQb x Vb) + tailor/sumV/residual epilogue -----------
// 2-phase double-buffered: counted vmcnt + raw s_barrier
__global__ __launch_bounds__(256) void k6_part(const unsigned short* __restrict__ KQb,
        const unsigned short* __restrict__ Vb, const float* __restrict__ dvec,
        const float* __restrict__ sumV, const float* __restrict__ gamma,
        float* __restrict__ out) {
    __shared__ __attribute__((aligned(16))) unsigned short la[2][128][64];
    __shared__ __attribute__((aligned(16))) unsigned short lb[2][128][64];
    int cpx = gridDim.x >> 3;
    int blk = ((int)blockIdx.x & 7) * cpx + ((int)blockIdx.x >> 3);  // XCD swizzle
    int b = blk >> 7, mt = (blk >> 5) & 3, lt = blk & 31;
    int M0 = mt * 128, L0 = lt * 128;
    int t = threadIdx.x;
    int w = t >> 6, lane = t & 63;
    int wr = w >> 1, wc = w & 1;
    int rl = lane >> 3;
    int cl = ((lane & 7) ^ rl) << 3;
    int lr = lane & 15, q4 = lane >> 4;
    int ch0 = (q4 ^ (lane & 7)) << 3;
    const unsigned short* pa = KQb + ((size_t)b * HE + M0) * HE;
    const unsigned short* pb = Vb + ((size_t)b * LL + L0) * HE;
    float gma = gamma[0];   // hoisted above prologue so vmcnt counting stays exact
    f32x4 acc[4][4] = {};

#define STAGE6(B, KB) do { \
    int _k0 = (KB) * 64; \
    _Pragma("unroll") \
    for (int p = 0; p < 4; p++) { \
        int r0 = p * 32 + w * 8; \
        gl16(pa + (size_t)(r0 + rl) * HE + _k0 + cl, &la[B][r0][0]); \
        gl16(pb + (size_t)(r0 + rl) * HE + _k0 + cl, &lb[B][r0][0]); \
    } } while (0)

    STAGE6(0, 0);  // prologue
    #pragma unroll
    for (int kb = 0; kb < 8; kb++) {
        int cur = kb & 1;
        if (kb < 7) {
            STAGE6(cur ^ 1, kb + 1);
            asm volatile("s_waitcnt vmcnt(8)" ::: "memory");
        } else {
            asm volatile("s_waitcnt vmcnt(0)" ::: "memory");
        }
        __builtin_amdgcn_s_barrier();
        #pragma unroll
        for (int ks = 0; ks < 2; ks++) {
            int colA = ch0 ^ (ks << 5);
            short8 af[4], bfr[4];
            #pragma unroll
            for (int i = 0; i < 4; i++)
                af[i] = *(const short8*)&la[cur][wr*64 + i*16 + lr][colA];
            #pragma unroll
            for (int j = 0; j < 4; j++)
                bfr[j] = *(const short8*)&lb[cur][wc*64 + j*16 + lr][colA];
            #pragma unroll
            for (int i = 0; i < 4; i++)
                #pragma unroll
                for (int j = 0; j < 4; j++)
                    acc[i][j] = __builtin_amdgcn_mfma_f32_16x16x32_bf16(af[i], bfr[j], acc[i][j], 0, 0, 0);
        }
        __builtin_amdgcn_s_barrier();
    }
#undef STAGE6
    #pragma unroll
    for (int j = 0; j < 4; j++) {
        int lglob = L0 + wc*64 + j*16 + lr;
        float dt = dvec[(size_t)b * LL + lglob];
        float tailor = 1.0f / (512.0f + dt);
        #pragma unroll
        for (int i = 0; i < 4; i++) {
            int m4 = M0 + wr*64 + i*16 + q4*4;
            size_t ofs = ((size_t)b * LL + lglob) * HE + m4;
            ushort4 rv = *(const ushort4*)(Vb + ((size_t)b * LL + lglob) * HE + m4);
            float4 vs = *(const float4*)(sumV + (size_t)b * HE + m4);
            float4 o;
            o.x = bf2f(rv.x) + gma * (vs.x + acc[i][j][0]) * tailor;
            o.y = bf2f(rv.y) + gma * (vs.y + acc[i][j][1]) * tailor;
            o.z = bf2f(rv.z) + gma * (vs.z + acc[i][j][2]) * tailor;
            o.w = bf2f(rv.w) + gma * (vs.w + acc[i][j][3]) * tailor;
            *(float4*)(out + ofs) = o;
        }
    }
}

extern "C" void kernel_launch(void* const* d_in, const int* in_sizes, int n_in,
                              void* d_out, int out_size, void* d_ws, size_t ws_size,
                              hipStream_t stream) {
    const float* q     = (const float*)d_in[0];
    const float* gamma = (const float*)d_in[4];
    float* out = (float*)d_out;
    char* ws = (char*)d_ws;
    // ws layout (~122 MiB; ws proven >= 189 MiB by rounds 4/5)
    float* sumV  = (float*)(ws);                          // 32 KiB
    float* cvec  = (float*)(ws + 65536);                  // 32 KiB
    float* invn  = (float*)(ws + 98304);                  // 32 KiB
    float* dvec  = (float*)(ws + 131072);                 // 256 KiB
    unsigned short* KQb = (unsigned short*)(ws + 524288);      // 8 MiB
    unsigned short* Vb  = (unsigned short*)(ws + 8912896);     // 64 MiB
    unsigned short* Gp  = (unsigned short*)(ws + 76021760);    // 40 MiB
    float* ps = (float*)(ws + 117964800);                 // 2 MiB
    float* pq = (float*)(ws + 120061952);                 // 2 MiB

    k1_stream<<<1024, 256, 0, stream>>>(q, Vb, ps, pq);
    k2_reduce<<<32,   256, 0, stream>>>(ps, pq, sumV, cvec, invn);
    k3_dvec  <<<2048, 256, 0, stream>>>(Vb, cvec, dvec);
    k4_gram  <<<1280, 256, 0, stream>>>(Vb, Gp);
    k5_reduce<<<160,  256, 0, stream>>>(Gp, invn, KQb);
    k6_part  <<<2048, 256, 0, stream>>>(KQb, Vb, dvec, sumV, gamma, out);
}

// Round 7
// 203.571 us; speedup vs baseline: 1.0008x; 1.0008x over previous
//
#include <hip/hip_runtime.h>

#define EPS 1e-6f
#define LL 4096
#define HE 512

typedef __attribute__((ext_vector_type(8))) short short8;
typedef __attribute__((ext_vector_type(4))) float f32x4;

__device__ __forceinline__ unsigned short f2bf(float f) {
    union { float f; unsigned u; } v; v.f = f;
    unsigned r = v.u + 0x7FFFu + ((v.u >> 16) & 1u);  // RNE
    return (unsigned short)(r >> 16);
}
__device__ __forceinline__ float bf2f(unsigned short s) {
    union { unsigned u; float f; } v; v.u = ((unsigned)s) << 16;
    return v.f;
}
// async global->LDS, 16B per lane; LDS dest = wave-uniform base + lane*16
__device__ __forceinline__ void gl16(const unsigned short* g, unsigned short* l) {
    __builtin_amdgcn_global_load_lds(
        (const __attribute__((address_space(1))) unsigned int*)(const void*)g,
        (__attribute__((address_space(3))) unsigned int*)(void*)l,
        16, 0, 0);
}

// ---- k1: pure streaming: q -> Vb (bf16 [l][n]) + column-stat partials ----
__global__ __launch_bounds__(256) void k1_stream(const float* __restrict__ q,
        unsigned short* __restrict__ Vb, float* __restrict__ ps,
        float* __restrict__ pq) {
    __shared__ float lds_s[4][512];
    __shared__ float lds_q[4][512];
    int blk = blockIdx.x;
    int b = blk >> 6, lt = blk & 63;
    int t = threadIdx.x;
    int oct = t & 63, w = t >> 6;
    size_t rowbase = (size_t)b * LL + lt * 64 + w * 16;
    const float* qb = q + rowbase * HE + oct * 8;
    unsigned short* vb = Vb + rowbase * HE + oct * 8;
    float s[8] = {}, qq[8] = {};
    #pragma unroll
    for (int r = 0; r < 16; r++) {
        float4 v0 = *(const float4*)(qb + (size_t)r * HE);
        float4 v1 = *(const float4*)(qb + (size_t)r * HE + 4);
        unsigned short e[8] = {f2bf(v0.x), f2bf(v0.y), f2bf(v0.z), f2bf(v0.w),
                               f2bf(v1.x), f2bf(v1.y), f2bf(v1.z), f2bf(v1.w)};
        short8 w8;
        #pragma unroll
        for (int c = 0; c < 8; c++) {
            w8[c] = (short)e[c];
            float x = bf2f(e[c]);
            s[c] += x; qq[c] += x * x;
        }
        *(short8*)(vb + (size_t)r * HE) = w8;
    }
    #pragma unroll
    for (int c = 0; c < 8; c++) {
        lds_s[w][oct * 8 + c] = s[c];
        lds_q[w][oct * 8 + c] = qq[c];
    }
    __syncthreads();
    #pragma unroll
    for (int h = 0; h < 2; h++) {
        int col = h * 256 + t;
        float ss = lds_s[0][col] + lds_s[1][col] + lds_s[2][col] + lds_s[3][col];
        float sq = lds_q[0][col] + lds_q[1][col] + lds_q[2][col] + lds_q[3][col];
        ps[(size_t)lt * 8192 + b * 512 + col] = ss;
        pq[(size_t)lt * 8192 + b * 512 + col] = sq;
    }
}

// ---- k2: reduce partials -> sumV, cvec, invn ----------------------------
__global__ __launch_bounds__(256) void k2_reduce(const float* __restrict__ ps,
        const float* __restrict__ pq, float* __restrict__ sumV,
        float* __restrict__ cvec, float* __restrict__ invn) {
    int i = blockIdx.x * 256 + threadIdx.x;   // 0..8191 = b*512 + n
    float s = 0.f, qq = 0.f;
    #pragma unroll 8
    for (int lt = 0; lt < 64; lt++) {
        s  += ps[(size_t)lt * 8192 + i];
        qq += pq[(size_t)lt * 8192 + i];
    }
    float inv = 1.0f / sqrtf(qq);
    sumV[i] = s;
    invn[i] = inv;
    cvec[i] = (s * inv + EPS) * inv;
}

// ---- k3: dvec[b,l] = sum_n Vb[l,n]*cvec[n]  (GEMV) ----------------------
__global__ __launch_bounds__(256) void k3_dvec(const unsigned short* __restrict__ Vb,
        const float* __restrict__ cvec, float* __restrict__ dvec) {
    int blk = blockIdx.x;
    int b = blk >> 7, lblk = blk & 127;
    int t = threadIdx.x;
    int lloc = t >> 3, j = t & 7;
    int l = lblk * 32 + lloc;
    const unsigned short* rowp = Vb + ((size_t)b * LL + l) * HE + j * 64;
    const float* cp = cvec + b * HE + j * 64;
    float d = 0.f;
    #pragma unroll
    for (int g = 0; g < 8; g++) {
        short8 v = *(const short8*)(rowp + g * 8);
        float4 c0 = *(const float4*)(cp + g * 8);
        float4 c1 = *(const float4*)(cp + g * 8 + 4);
        d += bf2f((unsigned short)v[0]) * c0.x + bf2f((unsigned short)v[1]) * c0.y
           + bf2f((unsigned short)v[2]) * c0.z + bf2f((unsigned short)v[3]) * c0.w
           + bf2f((unsigned short)v[4]) * c1.x + bf2f((unsigned short)v[5]) * c1.y
           + bf2f((unsigned short)v[6]) * c1.z + bf2f((unsigned short)v[7]) * c1.w;
    }
    d += __shfl_xor(d, 1); d += __shfl_xor(d, 2); d += __shfl_xor(d, 4);
    if (j == 0) dvec[(size_t)b * LL + l] = d;
}

// ---- k4: Gram partials from Vb (reg-staged in-LDS transpose, DOUBLE-BUFFERED)
// Per tile: lgkmcnt(0); s_barrier; then WRITE(next)+LOAD(tile+2)+MFMA(cur)
// all overlap in one phase. Buffer written at kb == buffer read at kb-1,
// separated by the barrier. Reg sets alternate: write set (kb+1)&1, load set kb&1.
__global__ __launch_bounds__(256) void k4_gram(const unsigned short* __restrict__ Vb,
        unsigned short* __restrict__ Gp) {
    __shared__ __attribute__((aligned(16))) unsigned short lt_a[2][128][72];
    __shared__ __attribute__((aligned(16))) unsigned short lt_b[2][128][72];
    int cpx = gridDim.x >> 3;
    int blk = ((int)blockIdx.x & 7) * cpx + ((int)blockIdx.x >> 3);  // XCD swizzle
    int b = blk / 80;
    int rem = blk - b * 80;
    int pair = rem >> 3, split = rem & 7;
    int nt = (pair < 4) ? 0 : (pair < 7) ? 1 : (pair < 9) ? 2 : 3;
    int off = (nt * (9 - nt)) >> 1;
    int mt = nt + pair - off;
    bool diag = (nt == mt);
    int N0 = nt * 128, M0 = mt * 128;
    int t = threadIdx.x;
    int w = t >> 6, lane = t & 63;
    int wr = w >> 1, wc = w & 1;
    int lr = lane & 15, q4 = lane >> 4;
    // staging map: 16 n-octets x 16 l-groups (4 rows each)
    int oct = t & 15;
    int l0 = (t >> 4) * 4;
    int lp = l0 ^ (8 * (oct & 7));   // XOR-swizzled l position
    const unsigned short* pa = Vb + ((size_t)b * LL + split * 512) * HE + N0 + oct * 8;
    const unsigned short* pb = Vb + ((size_t)b * LL + split * 512) * HE + M0 + oct * 8;
    f32x4 acc[4][4] = {};
    short8 ra[2][4], rb[2][4];

#define K4LOAD(KB, SET) do { \
    _Pragma("unroll") \
    for (int r = 0; r < 4; r++) { \
        size_t ro = (size_t)((KB) * 64 + l0 + r) * HE; \
        ra[SET][r] = *(const short8*)(pa + ro); \
        if (!diag) rb[SET][r] = *(const short8*)(pb + ro); \
    } } while (0)

#define K4WRITE(SET, BUF) do { \
    _Pragma("unroll") \
    for (int c = 0; c < 8; c++) { \
        uint2 da; \
        da.x = (unsigned)(unsigned short)ra[SET][0][c] | ((unsigned)(unsigned short)ra[SET][1][c] << 16); \
        da.y = (unsigned)(unsigned short)ra[SET][2][c] | ((unsigned)(unsigned short)ra[SET][3][c] << 16); \
        *(uint2*)&lt_a[BUF][oct * 8 + c][lp] = da; \
        if (!diag) { \
            uint2 db; \
            db.x = (unsigned)(unsigned short)rb[SET][0][c] | ((unsigned)(unsigned short)rb[SET][1][c] << 16); \
            db.y = (unsigned)(unsigned short)rb[SET][2][c] | ((unsigned)(unsigned short)rb[SET][3][c] << 16); \
            *(uint2*)&lt_b[BUF][oct * 8 + c][lp] = db; \
        } \
    } } while (0)

    K4LOAD(0, 0);
    K4WRITE(0, 0);
    K4LOAD(1, 1);
    #pragma unroll
    for (int kb = 0; kb < 8; kb++) {
        const int cur = kb & 1;
        asm volatile("s_waitcnt lgkmcnt(0)" ::: "memory");
        __builtin_amdgcn_s_barrier();
        asm volatile("" ::: "memory");
        if (kb < 7) K4WRITE(cur ^ 1, cur ^ 1);   // overlaps with MFMA(cur)
        if (kb < 6) K4LOAD(kb + 2, cur);         // overlaps with MFMA(cur)
        #pragma unroll
        for (int ks = 0; ks < 2; ks++) {
            short8 af[4], bfr[4];
            #pragma unroll
            for (int i = 0; i < 4; i++) {
                int row = wr * 64 + i * 16 + lr;
                int col = (ks * 32 + q4 * 8) ^ (8 * ((2 * i + (lr >> 3)) & 7));
                af[i] = *(const short8*)&lt_a[cur][row][col];
            }
            #pragma unroll
            for (int j = 0; j < 4; j++) {
                int row = wc * 64 + j * 16 + lr;
                int col = (ks * 32 + q4 * 8) ^ (8 * ((2 * j + (lr >> 3)) & 7));
                bfr[j] = diag ? *(const short8*)&lt_a[cur][row][col]
                              : *(const short8*)&lt_b[cur][row][col];
            }
            #pragma unroll
            for (int i = 0; i < 4; i++)
                #pragma unroll
                for (int j = 0; j < 4; j++)
                    acc[i][j] = __builtin_amdgcn_mfma_f32_16x16x32_bf16(af[i], bfr[j], acc[i][j], 0, 0, 0);
        }
    }
#undef K4LOAD
#undef K4WRITE
    // store bf16 partials, layout [ml*128 + nl] -> ushort4 along n
    size_t tbase = ((size_t)(b * 10 + pair) * 8 + split) * 16384;
    #pragma unroll
    for (int i = 0; i < 4; i++) {
        int nb = wr * 64 + i * 16 + q4 * 4;
        #pragma unroll
        for (int j = 0; j < 4; j++) {
            int ml = wc * 64 + j * 16 + lr;
            ushort4 wv;
            wv.x = f2bf(acc[i][j][0]); wv.y = f2bf(acc[i][j][1]);
            wv.z = f2bf(acc[i][j][2]); wv.w = f2bf(acc[i][j][3]);
            *(ushort4*)&Gp[tbase + (size_t)ml * 128 + nb] = wv;
        }
    }
}

// ---- k5: sum splits, scale by invn outer, write KQb both orientations ---
__global__ __launch_bounds__(256) void k5_reduce(const unsigned short* __restrict__ Gp,
        const float* __restrict__ invn, unsigned short* __restrict__ KQb) {
    __shared__ unsigned short lds_t[128][130];
    int blk = blockIdx.x;
    int b = blk / 10, pair = blk % 10;
    int nt = (pair < 4) ? 0 : (pair < 7) ? 1 : (pair < 9) ? 2 : 3;
    int off = (nt * (9 - nt)) >> 1;
    int mt = nt + pair - off;
    int N0 = nt * 128, M0 = mt * 128;
    int t = threadIdx.x;
    const unsigned short* gp = Gp + ((size_t)(b * 10 + pair) * 8) * 16384;
    const float* inb = invn + (size_t)b * HE;
    #pragma unroll 2
    for (int e = 0; e < 32; e++) {
        int idx = e * 512 + t * 2;           // [ml][nl] pairs
        int ml = idx >> 7, nl = idx & 127;
        float s0 = 0.f, s1 = 0.f;
        #pragma unroll
        for (int sp = 0; sp < 8; sp++) {
            unsigned g2 = *(const unsigned*)&gp[(size_t)sp * 16384 + idx];
            s0 += bf2f((unsigned short)(g2 & 0xFFFF));
            s1 += bf2f((unsigned short)(g2 >> 16));
        }
        float im = inb[M0 + ml];
        ushort2 v;
        v.x = f2bf(s0 * inb[N0 + nl] * im);
        v.y = f2bf(s1 * inb[N0 + nl + 1] * im);
        *(ushort2*)&KQb[((size_t)b * HE + M0 + ml) * HE + N0 + nl] = v;
        *(ushort2*)&lds_t[ml][nl] = v;
    }
    __syncthreads();
    #pragma unroll 2
    for (int e = 0; e < 32; e++) {
        int idx = e * 512 + t * 2;
        int nl = idx >> 7, ml = idx & 127;   // transposed roles
        ushort2 v;
        v.x = lds_t[ml][nl];
        v.y = lds_t[ml + 1][nl];
        *(ushort2*)&KQb[((size_t)b * HE + N0 + nl) * HE + M0 + ml] = v;
    }
}

// ---- k6: part GEMM (KQb x Vb) + tailor/sumV/residual epilogue -----------
// 2-phase double-buffered: counted vmcnt + raw s_barrier
__global__ __launch_bounds__(256) void k6_part(const unsigned short* __restrict__ KQb,
        const unsigned short* __restrict__ Vb, const float* __restrict__ dvec,
        const float* __restrict__ sumV, const float* __restrict__ gamma,
        float* __restrict__ out) {
    __shared__ __attribute__((aligned(16))) unsigned short la[2][128][64];
    __shared__ __attribute__((aligned(16))) unsigned short lb[2][128][64];
    int cpx = gridDim.x >> 3;
    int blk = ((int)blockIdx.x & 7) * cpx + ((int)blockIdx.x >> 3);  // XCD swizzle
    int b = blk >> 7, mt = (blk >> 5) & 3, lt = blk & 31;
    int M0 = mt * 128, L0 = lt * 128;
    int t = threadIdx.x;
    int w = t >> 6, lane = t & 63;
    int wr = w >> 1, wc = w & 1;
    int rl = lane >> 3;
    int cl = ((lane & 7) ^ rl) << 3;
    int lr = lane & 15, q4 = lane >> 4;
    int ch0 = (q4 ^ (lane & 7)) << 3;
    const unsigned short* pa = KQb + ((size_t)b * HE + M0) * HE;
    const unsigned short* pb = Vb + ((size_t)b * LL + L0) * HE;
    float gma = gamma[0];   // hoisted above prologue so vmcnt counting stays exact
    f32x4 acc[4][4] = {};

#define STAGE6(B, KB) do { \
    int _k0 = (KB) * 64; \
    _Pragma("unroll") \
    for (int p = 0; p < 4; p++) { \
        int r0 = p * 32 + w * 8; \
        gl16(pa + (size_t)(r0 + rl) * HE + _k0 + cl, &la[B][r0][0]); \
        gl16(pb + (size_t)(r0 + rl) * HE + _k0 + cl, &lb[B][r0][0]); \
    } } while (0)

    STAGE6(0, 0);  // prologue
    #pragma unroll
    for (int kb = 0; kb < 8; kb++) {
        int cur = kb & 1;
        if (kb < 7) {
            STAGE6(cur ^ 1, kb + 1);
            asm volatile("s_waitcnt vmcnt(8)" ::: "memory");
        } else {
            asm volatile("s_waitcnt vmcnt(0)" ::: "memory");
        }
        __builtin_amdgcn_s_barrier();
        #pragma unroll
        for (int ks = 0; ks < 2; ks++) {
            int colA = ch0 ^ (ks << 5);
            short8 af[4], bfr[4];
            #pragma unroll
            for (int i = 0; i < 4; i++)
                af[i] = *(const short8*)&la[cur][wr*64 + i*16 + lr][colA];
            #pragma unroll
            for (int j = 0; j < 4; j++)
                bfr[j] = *(const short8*)&lb[cur][wc*64 + j*16 + lr][colA];
            #pragma unroll
            for (int i = 0; i < 4; i++)
                #pragma unroll
                for (int j = 0; j < 4; j++)
                    acc[i][j] = __builtin_amdgcn_mfma_f32_16x16x32_bf16(af[i], bfr[j], acc[i][j], 0, 0, 0);
        }
        __builtin_amdgcn_s_barrier();
    }
#undef STAGE6
    #pragma unroll
    for (int j = 0; j < 4; j++) {
        int lglob = L0 + wc*64 + j*16 + lr;
        float dt = dvec[(size_t)b * LL + lglob];
        float tailor = 1.0f / (512.0f + dt);
        #pragma unroll
        for (int i = 0; i < 4; i++) {
            int m4 = M0 + wr*64 + i*16 + q4*4;
            size_t ofs = ((size_t)b * LL + lglob) * HE + m4;
            ushort4 rv = *(const ushort4*)(Vb + ((size_t)b * LL + lglob) * HE + m4);
            float4 vs = *(const float4*)(sumV + (size_t)b * HE + m4);
            float4 o;
            o.x = bf2f(rv.x) + gma * (vs.x + acc[i][j][0]) * tailor;
            o.y = bf2f(rv.y) + gma * (vs.y + acc[i][j][1]) * tailor;
            o.z = bf2f(rv.z) + gma * (vs.z + acc[i][j][2]) * tailor;
            o.w = bf2f(rv.w) + gma * (vs.w + acc[i][j][3]) * tailor;
            *(float4*)(out + ofs) = o;
        }
    }
}

extern "C" void kernel_launch(void* const* d_in, const int* in_sizes, int n_in,
                              void* d_out, int out_size, void* d_ws, size_t ws_size,
                              hipStream_t stream) {
    const float* q     = (const float*)d_in[0];
    const float* gamma = (const float*)d_in[4];
    float* out = (float*)d_out;
    char* ws = (char*)d_ws;
    // ws layout (~122 MiB; ws proven >= 189 MiB by rounds 4/5)
    float* sumV  = (float*)(ws);                          // 32 KiB
    float* cvec  = (float*)(ws + 65536);                  // 32 KiB
    float* invn  = (float*)(ws + 98304);                  // 32 KiB
    float* dvec  = (float*)(ws + 131072);                 // 256 KiB
    unsigned short* KQb = (unsigned short*)(ws + 524288);      // 8 MiB
    unsigned short* Vb  = (unsigned short*)(ws + 8912896);     // 64 MiB
    unsigned short* Gp  = (unsigned short*)(ws + 76021760);    // 40 MiB
    float* ps = (float*)(ws + 117964800);                 // 2 MiB
    float* pq = (float*)(ws + 120061952);                 // 2 MiB

    k1_stream<<<1024, 256, 0, stream>>>(q, Vb, ps, pq);
    k2_reduce<<<32,   256, 0, stream>>>(ps, pq, sumV, cvec, invn);
    k3_dvec  <<<2048, 256, 0, stream>>>(Vb, cvec, dvec);
    k4_gram  <<<1280, 256, 0, stream>>>(Vb, Gp);
    k5_reduce<<<160,  256, 0, stream>>>(Gp, invn, KQb);
    k6_part  <<<2048, 256, 0, stream>>>(KQb, Vb, dvec, sumV, gamma, out);
}